// Round 4
// baseline (146.774 us; speedup 1.0000x reference)
//
#include <hip/hip_runtime.h>

#define NB    16
#define CIN   16
#define COUT  32
#define DIN   32
#define DOUT  30
#define XS_OFF 57344          // byte offset of xs inside d_ws (A-frags live below)

typedef __attribute__((ext_vector_type(8)))  short  short8;
typedef __attribute__((ext_vector_type(16))) float  f32x16;

static __device__ __forceinline__ unsigned short f2bf_rne(float f) {
    unsigned int u = __builtin_bit_cast(unsigned int, f);
    u += 0x7fffu + ((u >> 16) & 1u);
    return (unsigned short)(u >> 16);
}
static __device__ __forceinline__ float bf2f(unsigned short s) {
    unsigned int u = ((unsigned int)s) << 16;
    return __builtin_bit_cast(float, u);
}

// ---------------- Kernel 1: prep ----------------
// blocks 0..4095: split+transpose x into xs (channel-last bf16 hi/lo):
//   row rid=(b*32+d)*32+h is 2048B: hi chunks c=0..63 (c=2w+octet, 16B each), then lo.
// blocks 4096..4122: repack W into MFMA A-fragments (hi at chunk 0, lo at chunk 1728).
__global__ __launch_bounds__(256) void prep_kernel(const float* __restrict__ x,
                                                   const float* __restrict__ wgt,
                                                   char* __restrict__ ws) {
    const int bx  = blockIdx.x;
    const int tid = threadIdx.x;
    if (bx < 4096) {
        const int wy = tid >> 6, lane = tid & 63;
        const int rid = bx * 4 + wy;             // 0..16383
        const int h = rid & 31, d = (rid >> 5) & 31, b = rid >> 10;
        const int w = lane >> 1, oc = lane & 1;  // chunk c = 2w+oc = lane
        const float* xp = x + ((((size_t)(b * 16 + oc * 8) * 32 + d) * 32 + h) * 32 + w);
        short8 vh, vl;
#pragma unroll
        for (int j = 0; j < 8; ++j) {
            float f = xp[j * 32768];             // ci = oc*8 + j
            unsigned short hb = f2bf_rne(f);
            vh[j] = (short)hb;
            vl[j] = (short)f2bf_rne(f - bf2f(hb));
        }
        char* row = ws + XS_OFF + (size_t)rid * 2048;
        *(short8*)(row + lane * 16)        = vh;
        *(short8*)(row + 1024 + lane * 16) = vl;
    } else if (tid < 64) {
        const int s = bx - 4096;                 // 0..26
        const int l = tid;
        const int co = l & 31, ci0 = (l >> 5) * 8;
        short8 vh, vl;
#pragma unroll
        for (int j = 0; j < 8; ++j) {
            float f = wgt[co * (CIN * 27) + (ci0 + j) * 27 + s];
            unsigned short hb = f2bf_rne(f);
            vh[j] = (short)hb;
            vl[j] = (short)f2bf_rne(f - bf2f(hb));
        }
        ((short8*)ws)[s * 64 + l]           = vh;
        ((short8*)ws)[1728 + s * 64 + l]    = vl;
    }
}

// ---------------- Kernel 2: main conv ----------------
// Block (htile 0..7, d2 0..14, b): 4 waves; wave wy -> output row h=4*htile+wy,
// outputs d0=2*d2 and d0+1, all 32 co. Stages 4 input planes x 6 h-rows,
// pre-split bf16 hi/lo, XOR-swizzled for conflict-free b128 reads. 48KB LDS.
__global__ __launch_bounds__(256) void conv_main(
    const char* __restrict__ ws,
    const float* __restrict__ cbias,
    const float* __restrict__ scal,
    const float* __restrict__ bpar,
    float* __restrict__ out)
{
    __shared__ __align__(16) short sx[24576];   // 48 slots x 512 shorts = 49152 B
    __shared__ float sp[96];

    const int htile = blockIdx.x;
    const int d2    = blockIdx.y;
    const int b     = blockIdx.z;
    const int tid  = threadIdx.x;
    const int wy   = tid >> 6;
    const int lane = tid & 63;

    if (tid < 32) {
        sp[tid]      = cbias[tid];
        sp[32 + tid] = scal[tid];
        sp[64 + tid] = bpar[tid];
    }

    const int h0 = htile * 4, d0 = d2 * 2;
    const char* xbase = ws + XS_OFF;
    const int psw = (lane ^ ((lane >> 3) & 7)) * 8;   // swizzled chunk offset (shorts)

    // stage 48 rows of 1KB (plane p 0..3, h-row 0..5, buf hi/lo); wave wy does 12
#pragma unroll
    for (int r = wy * 12; r < wy * 12 + 12; ++r) {
        const int buf = r & 1, pr = r >> 1;           // pr = p*6+row
        const int p = pr / 6, row = pr - p * 6;
        int hin = h0 + row; if (hin > 31) hin = 31;   // htile 7 halo clamp (feeds masked rows only)
        const int rid = (b * 32 + d0 + p) * 32 + hin;
        const short8 v = *((const short8*)(xbase + (size_t)rid * 2048 + buf * 1024) + lane);
        *(short8*)(sx + (pr * 2 + buf) * 512 + psw) = v;
    }
    __syncthreads();

    const int h = h0 + wy;
    if (h >= DOUT) return;          // only barrier is above

    const int n  = lane & 31;       // output w (30 valid + 2 pad)
    const int oc = lane >> 5;       // ci-octet
    int cofs[3];
#pragma unroll
    for (int kw = 0; kw < 3; ++kw) {
        int wc = n + kw; if (wc > 31) wc = 31;
        const int c = 2 * wc + oc;
        cofs[kw] = (c ^ ((c >> 3) & 7)) * 8;
    }

    f32x16 acc0, acc1;
#pragma unroll
    for (int i = 0; i < 16; ++i) { acc0[i] = 0.0f; acc1[i] = 0.0f; }

    const short8* wa = (const short8*)ws;
#pragma unroll
    for (int kh = 0; kh < 3; ++kh) {
        const int rowi = wy + kh;
#pragma unroll
        for (int kw = 0; kw < 3; ++kw) {
            short8 bh[4], bl[4];
#pragma unroll
            for (int p = 0; p < 4; ++p) {             // reused across kd (plane = dd+kd)
                const short* slot = sx + ((p * 6 + rowi) * 2) * 512;
                bh[p] = *(const short8*)(slot + cofs[kw]);
                bl[p] = *(const short8*)(slot + 512 + cofs[kw]);
            }
#pragma unroll
            for (int kd = 0; kd < 3; ++kd) {
                const int s = kd * 9 + kh * 3 + kw;
                short8 ah = wa[s * 64 + lane];
                short8 al = wa[1728 + s * 64 + lane];
                acc0 = __builtin_amdgcn_mfma_f32_32x32x16_bf16(ah, bh[kd],     acc0, 0, 0, 0);
                acc1 = __builtin_amdgcn_mfma_f32_32x32x16_bf16(ah, bh[kd + 1], acc1, 0, 0, 0);
                acc0 = __builtin_amdgcn_mfma_f32_32x32x16_bf16(ah, bl[kd],     acc0, 0, 0, 0);
                acc1 = __builtin_amdgcn_mfma_f32_32x32x16_bf16(ah, bl[kd + 1], acc1, 0, 0, 0);
                acc0 = __builtin_amdgcn_mfma_f32_32x32x16_bf16(al, bh[kd],     acc0, 0, 0, 0);
                acc1 = __builtin_amdgcn_mfma_f32_32x32x16_bf16(al, bh[kd + 1], acc1, 0, 0, 0);
            }
        }
    }

    if (n < DOUT) {
        const int ob = b * (COUT * 27000) + h * 30 + n;
#pragma unroll
        for (int r = 0; r < 16; ++r) {
            const int co = (r & 3) + 8 * (r >> 2) + 4 * oc;
            float y0 = acc0[r] + sp[co];
            float t0 = y0 * sp[32 + co];
            float th0 = 1.0f - 2.0f / (__expf(2.0f * t0) + 1.0f);
            float z0 = th0 * sp[64 + co];
            out[ob + co * 27000 + d0 * 900] = 1.0f / (1.0f + __expf(-z0));

            float y1 = acc1[r] + sp[co];
            float t1 = y1 * sp[32 + co];
            float th1 = 1.0f - 2.0f / (__expf(2.0f * t1) + 1.0f);
            float z1 = th1 * sp[64 + co];
            out[ob + co * 27000 + (d0 + 1) * 900] = 1.0f / (1.0f + __expf(-z1));
        }
    }
}

// ---------------- Fallback A (round-3, needs 55296B ws) ----------------
__global__ __launch_bounds__(64) void repack_w_fb(const float* __restrict__ wgt,
                                                  short* __restrict__ ws) {
    const int s = blockIdx.x, l = threadIdx.x;
    const int co = l & 31, ci0 = (l >> 5) * 8;
    short8 vh, vl;
#pragma unroll
    for (int j = 0; j < 8; ++j) {
        float f = wgt[co * (CIN * 27) + (ci0 + j) * 27 + s];
        unsigned short hb = f2bf_rne(f);
        vh[j] = (short)hb;
        vl[j] = (short)f2bf_rne(f - bf2f(hb));
    }
    ((short8*)ws)[s * 64 + l]           = vh;
    ((short8*)ws)[27 * 64 + s * 64 + l] = vl;
}

__global__ __launch_bounds__(256) void conv3d_mfma_fb(
    const float* __restrict__ x, const short* __restrict__ wsA,
    const float* __restrict__ cbias, const float* __restrict__ scal,
    const float* __restrict__ bpar, float* __restrict__ out)
{
    __shared__ short sx[2 * 9216];
    __shared__ float sp[96];
    const int htile = blockIdx.x, d = blockIdx.y, b = blockIdx.z;
    const int tid = threadIdx.x, wy = tid >> 6, lane = tid & 63;
    if (tid < 32) { sp[tid] = cbias[tid]; sp[32 + tid] = scal[tid]; sp[64 + tid] = bpar[tid]; }
    const int h0 = htile * 4;
    const int xb = b * (CIN * DIN * DIN * DIN);
    for (int c = tid; c < 1152; c += 256) {
        const int hi8 = c & 1, r2 = c >> 1, w = r2 & 31, rr = r2 >> 5;
        const int dz = rr / 6, row = rr - dz * 6;
        int h_in = h0 + row; if (h_in > 31) h_in = 31;
        const int gbase = xb + (hi8 * 8) * (DIN * DIN * DIN) + (d + dz) * (DIN * DIN) + h_in * DIN + w;
        short8 vh, vl;
#pragma unroll
        for (int j = 0; j < 8; ++j) {
            float f = x[gbase + j * (DIN * DIN * DIN)];
            unsigned short hb = f2bf_rne(f);
            vh[j] = (short)hb; vl[j] = (short)f2bf_rne(f - bf2f(hb));
        }
        *(short8*)(sx + c * 8) = vh;
        *(short8*)(sx + 9216 + c * 8) = vl;
    }
    __syncthreads();
    const int h = h0 + wy;
    if (h >= DOUT) return;
    const int n = lane & 31, hi = lane >> 5;
    int wofs[3];
#pragma unroll
    for (int kw = 0; kw < 3; ++kw) { int wc = n + kw; if (wc > 31) wc = 31; wofs[kw] = wc * 16 + hi * 8; }
    f32x16 acc;
#pragma unroll
    for (int i = 0; i < 16; ++i) acc[i] = 0.0f;
    const short8* wa = (const short8*)wsA;
#pragma unroll
    for (int kd = 0; kd < 3; ++kd)
#pragma unroll
        for (int kh = 0; kh < 3; ++kh) {
            const int rbase = (kd * 6 + wy + kh) * (32 * 16);
#pragma unroll
            for (int kw = 0; kw < 3; ++kw) {
                const int s = kd * 9 + kh * 3 + kw;
                short8 ah = wa[s * 64 + lane];
                short8 al = wa[1728 + s * 64 + lane];
                short8 bh = *(const short8*)(sx + rbase + wofs[kw]);
                short8 bl = *(const short8*)(sx + 9216 + rbase + wofs[kw]);
                acc = __builtin_amdgcn_mfma_f32_32x32x16_bf16(ah, bh, acc, 0, 0, 0);
                acc = __builtin_amdgcn_mfma_f32_32x32x16_bf16(ah, bl, acc, 0, 0, 0);
                acc = __builtin_amdgcn_mfma_f32_32x32x16_bf16(al, bh, acc, 0, 0, 0);
            }
        }
    if (n < DOUT) {
        const int obase = b * (COUT * 27000) + d * 900 + h * 30 + n;
#pragma unroll
        for (int r = 0; r < 16; ++r) {
            const int co = (r & 3) + 8 * (r >> 2) + 4 * hi;
            float y = acc[r] + sp[co];
            float t = y * sp[32 + co];
            float th = 1.0f - 2.0f / (__expf(2.0f * t) + 1.0f);
            float z = th * sp[64 + co];
            out[obase + co * 27000] = 1.0f / (1.0f + __expf(-z));
        }
    }
}

// ---------------- Fallback B (round-2 direct, no ws) ----------------
__global__ __launch_bounds__(256) void conv3d_direct_fb(
    const float* __restrict__ x, const float* __restrict__ wgt,
    const float* __restrict__ cbias, const float* __restrict__ scal,
    const float* __restrict__ bpar, float* __restrict__ out)
{
    __shared__ float sw[CIN * 27];
    const int bx = blockIdx.x, co = blockIdx.y, b = blockIdx.z;
    const int tid = threadIdx.y * 32 + threadIdx.x;
    for (int i = tid; i < CIN * 27; i += 256) sw[i] = wgt[co * (CIN * 27) + i];
    __syncthreads();
    const float bias = cbias[co], s = scal[co], bp = bpar[co];
    const int dt = bx & 7, ht = bx >> 3;
    const int d0 = dt * 4, h = ht * 8 + threadIdx.y, w = threadIdx.x;
    if (w >= DOUT || h >= DOUT) return;
    int rowoff[6];
#pragma unroll
    for (int dz = 0; dz < 6; ++dz) { int dd = d0 + dz; if (dd > 31) dd = 31; rowoff[dz] = dd * 1024; }
    float acc[4] = {0.f, 0.f, 0.f, 0.f};
    const int xb = b * (CIN * 32768);
    for (int ci = 0; ci < CIN; ++ci) {
        const int cioff = xb + ci * 32768;
        const float* swc = &sw[ci * 27];
#pragma unroll
        for (int kh = 0; kh < 3; ++kh) {
            const int hbase = cioff + (h + kh) * DIN + w;
#pragma unroll
            for (int kw = 0; kw < 3; ++kw) {
                float xv[6];
#pragma unroll
                for (int dz = 0; dz < 6; ++dz) xv[dz] = x[hbase + kw + rowoff[dz]];
#pragma unroll
                for (int kd = 0; kd < 3; ++kd) {
                    const float wv = swc[(kd * 3 + kh) * 3 + kw];
#pragma unroll
                    for (int dd = 0; dd < 4; ++dd) acc[dd] = fmaf(xv[dd + kd], wv, acc[dd]);
                }
            }
        }
    }
    const int obase = (b * COUT + co) * 27000 + h * 30 + w;
#pragma unroll
    for (int dd = 0; dd < 4; ++dd) {
        const int d = d0 + dd;
        if (d < DOUT) {
            float y = acc[dd] + bias;
            float t = y * s;
            float th = 1.0f - 2.0f / (__expf(2.0f * t) + 1.0f);
            float z = th * bp;
            out[obase + d * 900] = 1.0f / (1.0f + __expf(-z));
        }
    }
}

extern "C" void kernel_launch(void* const* d_in, const int* in_sizes, int n_in,
                              void* d_out, int out_size, void* d_ws, size_t ws_size,
                              hipStream_t stream) {
    const float* x     = (const float*)d_in[0];
    const float* wgt   = (const float*)d_in[1];
    const float* cbias = (const float*)d_in[2];
    const float* scal  = (const float*)d_in[3];
    const float* bpar  = (const float*)d_in[4];
    float* out = (float*)d_out;

    const size_t need_full = (size_t)XS_OFF + (size_t)16384 * 2048;   // ~33.6 MB
    if (ws_size >= need_full) {
        char* ws = (char*)d_ws;
        hipLaunchKernelGGL(prep_kernel, dim3(4096 + 27), dim3(256), 0, stream, x, wgt, ws);
        hipLaunchKernelGGL(conv_main, dim3(8, 15, NB), dim3(256), 0, stream,
                           ws, cbias, scal, bpar, out);
    } else if (ws_size >= 55296) {
        short* ws = (short*)d_ws;
        hipLaunchKernelGGL(repack_w_fb, dim3(27), dim3(64), 0, stream, wgt, ws);
        hipLaunchKernelGGL(conv3d_mfma_fb, dim3(8, DOUT, NB), dim3(256), 0, stream,
                           x, ws, cbias, scal, bpar, out);
    } else {
        hipLaunchKernelGGL(conv3d_direct_fb, dim3(32, COUT, NB), dim3(32, 8), 0, stream,
                           x, wgt, cbias, scal, bpar, out);
    }
}